// Round 4
// baseline (255.146 us; speedup 1.0000x reference)
//
#include <hip/hip_runtime.h>

#define HDIM  256
#define YP    264              // padded Y row length in bf16 elems
#define SPBM  4                // samples per block
#define MROWS (SPBM * 8)       // 32 jet rows per block

typedef unsigned short u16;
typedef __attribute__((ext_vector_type(8))) short  short8;   // 8 bf16 (4 VGPRs)
typedef __attribute__((ext_vector_type(4))) float  f32x4;    // MFMA acc

// Row permutation: physical row R for (sample s=0..3, channel c=0..7):
//   R = 16*(c>>2) + 4*s + (c&3)
// => tile0 (rows 0..15)  = channels 0..3 (v,g0,g1,g2), sample = lane group g
//    tile1 (rows 16..31) = channels 4..7 (g3,s0,s1,s2), same lane group
// so the jet nonlinearity is PER-LANE: no cross-lane shuffles in the epilogue.

__device__ __forceinline__ float bf2f(u16 u) {
    union { unsigned int i; float f; } v; v.i = ((unsigned int)u) << 16; return v.f;
}
// cheap round-half-up bf16 (2 VALU instr); fine vs 3% abs threshold
__device__ __forceinline__ u16 f2bf(float f) {
    union { float f; unsigned int u; } v; v.f = f;
    return (u16)((v.u + 0x8000u) >> 16);
}
// proper RNE, used once in prepass for weights
__device__ __forceinline__ u16 f2bf_rne(float f) {
    union { float f; unsigned int u; } v; v.f = f;
    unsigned int r = v.u + 0x7fffu + ((v.u >> 16) & 1u);
    return (u16)(r >> 16);
}
// tanh(x) = 1 - 2/(e^{2x}+1) on raw v_exp_f32 / v_rcp_f32 (~4 instr, NaN-free)
__device__ __forceinline__ float fast_tanh(float x) {
    const float e = __builtin_amdgcn_exp2f(x * 2.885390081777927f); // e^{2x}
    const float r = __builtin_amdgcn_rcpf(e + 1.f);
    return 1.f - 2.f * r;
}

// ---- prepass: LDS-tiled transpose W[k][n] f32 -> Wt[n][k] bf16 (W1,W2,W3),
// ---- plus Wo[k][2] -> Wob[2][256] bf16 at ws + 3*65536.
// 97 blocks (32k x 64n tiles, 32 per matrix).
__global__ __launch_bounds__(256)
void prep_w(const float* __restrict__ W1, const float* __restrict__ W2,
            const float* __restrict__ W3, const float* __restrict__ Wo,
            u16* __restrict__ ws) {
    const int bid = blockIdx.x;
    const int tid = threadIdx.x;
    if (bid == 96) {
#pragma unroll
        for (int oc = 0; oc < 2; ++oc)
            ws[3 * 65536 + oc * 256 + tid] = f2bf_rne(Wo[tid * 2 + oc]);
        return;
    }
    const int which = bid >> 5;          // 0..2
    const int tile  = bid & 31;          // 32 tiles: 8 k-tiles x 4 n-tiles
    const int k0 = (tile & 7) * 32;
    const int n0 = (tile >> 3) * 64;
    const float* W = (which == 0) ? W1 : ((which == 1) ? W2 : W3);
    __shared__ float T[32][65];
    const int rk = tid >> 4;             // 0..15
    const int rn = (tid & 15) * 4;       // 0..60
#pragma unroll
    for (int rep = 0; rep < 2; ++rep) {
        const float4 v = *(const float4*)(W + (k0 + rep * 16 + rk) * 256 + n0 + rn);
        T[rep * 16 + rk][rn + 0] = v.x;
        T[rep * 16 + rk][rn + 1] = v.y;
        T[rep * 16 + rk][rn + 2] = v.z;
        T[rep * 16 + rk][rn + 3] = v.w;
    }
    __syncthreads();
    const int wn = tid >> 2;             // 0..63
    const int wk = (tid & 3) * 8;        // 0,8,16,24
    short8 o;
#pragma unroll
    for (int i = 0; i < 8; ++i)
        o[i] = (short)f2bf_rne(T[wk + i][wn]);
    *(short8*)(ws + which * 65536 + (n0 + wn) * 256 + k0 + wk) = o;
}

// ---- one hidden layer: Y(LDS, 32x256 bf16 jets) @ W(256x256) -> jets, in place ----
// 4 waves: wave wv owns all 32 rows x cols wv*64..+63.  acc[2][4] = 32 VGPRs.
// C/D: col=lane&15, row=(lane>>4)*4+reg.  A: A[m=lane&15][k=8*(lane>>4)+j].
__device__ __forceinline__ void hidden_layer_mfma(u16* __restrict__ Y,
                                                  const u16* __restrict__ Wt,
                                                  const float* __restrict__ b,
                                                  int l, int wv) {
    const int lm    = l & 15;
    const int lk8   = (l >> 4) * 8;
    const int nbase = wv * 64;

    f32x4 acc[2][4];
#pragma unroll
    for (int mt = 0; mt < 2; ++mt)
#pragma unroll
        for (int nt = 0; nt < 4; ++nt) acc[mt][nt] = (f32x4){0.f, 0.f, 0.f, 0.f};

#pragma unroll
    for (int ks = 0; ks < 8; ++ks) {
        const int kk = ks * 32 + lk8;
        short8 a[2], bf[4];
#pragma unroll
        for (int mt = 0; mt < 2; ++mt)
            a[mt] = *(const short8*)(Y + (mt * 16 + lm) * YP + kk);
#pragma unroll
        for (int nt = 0; nt < 4; ++nt)
            bf[nt] = *(const short8*)(Wt + ((nbase + nt * 16 + lm) << 8) + kk);
#pragma unroll
        for (int mt = 0; mt < 2; ++mt)
#pragma unroll
            for (int nt = 0; nt < 4; ++nt)
                acc[mt][nt] = __builtin_amdgcn_mfma_f32_16x16x32_bf16(
                    a[mt], bf[nt], acc[mt][nt], 0, 0, 0);
    }

    float bias[4];
#pragma unroll
    for (int nt = 0; nt < 4; ++nt) bias[nt] = b[nbase + nt * 16 + lm];

    __syncthreads();   // all waves done READING Y before anyone overwrites it

    const int g = l >> 4;    // sample index 0..3
#pragma unroll
    for (int nt = 0; nt < 4; ++nt) {
        const f32x4 ulo = acc[0][nt];   // v,g0,g1,g2 preacts of sample g
        const f32x4 uhi = acc[1][nt];   // g3,s0,s1,s2 preacts of sample g
        const float ty = fast_tanh(ulo[0] + bias[nt]);
        const float t  = 1.f - ty * ty;
        const float m  = -2.f * ty * t;
        const int n = nbase + nt * 16 + lm;
        u16* ylo = Y + (4 * g) * YP + n;
        u16* yhi = ylo + 16 * YP;
        ylo[0 * YP] = f2bf(ty);
        ylo[1 * YP] = f2bf(t * ulo[1]);
        ylo[2 * YP] = f2bf(t * ulo[2]);
        ylo[3 * YP] = f2bf(t * ulo[3]);
        yhi[0 * YP] = f2bf(t * uhi[0]);
        yhi[1 * YP] = f2bf(t * uhi[1] + m * ulo[1] * ulo[1]);
        yhi[2 * YP] = f2bf(t * uhi[2] + m * ulo[2] * ulo[2]);
        yhi[3 * YP] = f2bf(t * uhi[3] + m * ulo[3] * ulo[3]);
    }
    __syncthreads();
}

__global__ __launch_bounds__(256, 5)
void mlp_jet_mfma(const float* __restrict__ x,
                  const float* __restrict__ W0, const float* __restrict__ b0,
                  const float* __restrict__ b1, const float* __restrict__ b2,
                  const float* __restrict__ b3, const float* __restrict__ bo,
                  const u16* __restrict__ Wt,   // 3 x Wt[n][k] bf16, + Wob[2][256]
                  float* __restrict__ out, int nB) {
    __shared__ __align__(16) u16 Y[MROWS * YP];
    __shared__ float4 xs4[SPBM];
    __shared__ float  part[MROWS][2];

    const int tid = threadIdx.x;
    const int wv  = tid >> 6;            // 0..3
    const int l   = tid & 63;
    const int lm  = l & 15;
    const int lk8 = (l >> 4) * 8;
    const int n0  = blockIdx.x * SPBM;

    // ---- layer 0: 4 -> 256, VALU ----
    if (tid < SPBM) xs4[tid] = *(const float4*)(x + (n0 + tid) * 4);
    __syncthreads();
    {
        const int n = tid;
        const float w0 = W0[0 * HDIM + n], w1 = W0[1 * HDIM + n];
        const float w2 = W0[2 * HDIM + n], w3 = W0[3 * HDIM + n];
        const float bb = b0[n];
#pragma unroll
        for (int s = 0; s < SPBM; ++s) {
            const float4 xv = xs4[s];
            const float u  = xv.x * w0 + xv.y * w1 + xv.z * w2 + xv.w * w3 + bb;
            const float ty = fast_tanh(u);
            const float t  = 1.f - ty * ty;
            const float m  = -2.f * ty * t;
            // permuted rows: ch0..3 at 4s.., ch4..7 at 16+4s..
            u16* ylo = Y + (4 * s) * YP + n;
            u16* yhi = ylo + 16 * YP;
            ylo[0 * YP] = f2bf(ty);
            ylo[1 * YP] = f2bf(t * w0);
            ylo[2 * YP] = f2bf(t * w1);
            ylo[3 * YP] = f2bf(t * w2);
            yhi[0 * YP] = f2bf(t * w3);
            yhi[1 * YP] = f2bf(m * w0 * w0);
            yhi[2 * YP] = f2bf(m * w1 * w1);
            yhi[3 * YP] = f2bf(m * w2 * w2);
        }
    }
    __syncthreads();

    // ---- 3 hidden layers on the matrix pipe ----
    hidden_layer_mfma(Y, Wt + 0 * 65536, b1, l, wv);
    hidden_layer_mfma(Y, Wt + 1 * 65536, b2, l, wv);
    hidden_layer_mfma(Y, Wt + 2 * 65536, b3, l, wv);

    // ---- output head on MFMA: waves 0,1 take physical rows wv*16..wv*16+15 ----
    if (wv < 2) {
        const u16* wob = Wt + 3 * 65536;
        f32x4 h = (f32x4){0.f, 0.f, 0.f, 0.f};
#pragma unroll
        for (int ks = 0; ks < 8; ++ks) {
            const int kk = ks * 32 + lk8;
            const short8 a = *(const short8*)(Y + (wv * 16 + lm) * YP + kk);
            short8 bfr = (short8){0,0,0,0,0,0,0,0};
            if (lm < 2) bfr = *(const short8*)(wob + lm * 256 + kk);
            h = __builtin_amdgcn_mfma_f32_16x16x32_bf16(a, bfr, h, 0, 0, 0);
        }
        if (lm < 2) {
#pragma unroll
            for (int r = 0; r < 4; ++r)
                part[wv * 16 + (l >> 4) * 4 + r][lm] = h[r];
        }
    }
    __syncthreads();

    if (tid < SPBM) {
        const int s = tid;
        float q0[8], q1[8];
#pragma unroll
        for (int ch = 0; ch < 8; ++ch) {
            const int R = 16 * (ch >> 2) + 4 * s + (ch & 3);
            q0[ch] = part[R][0];
            q1[ch] = part[R][1];
        }
        const float c0  = q0[0] + bo[0];
        const float Fi  = q1[0] + bo[1];
        const float cg0 = q0[1], cg1 = q0[2], cg2 = q0[3];
        const float ct  = q0[4];                 // dc/dx_3 (TDIM)
        const float fg0 = q1[1], fg1 = q1[2], fg2 = q1[3];
        const float trHc  = q0[5] + q0[6] + q0[7];
        const float fiLap = q1[5] + q1[6] + q1[7];
        const float jd = -trHc
                         - (cg0 * fg0 + cg1 * fg1 + cg2 * fg2 + c0 * fiLap)
                         + 0.1f * (cg0 + cg1 + cg2);
        const int n = n0 + s;
        out[0 * nB + n]         = c0;
        out[1 * nB + n]         = ct;
        out[2 * nB + 3 * n + 0] = cg0;
        out[2 * nB + 3 * n + 1] = cg1;
        out[2 * nB + 3 * n + 2] = cg2;
        out[5 * nB + n]         = Fi;
        out[6 * nB + 3 * n + 0] = fg0;
        out[6 * nB + 3 * n + 1] = fg1;
        out[6 * nB + 3 * n + 2] = fg2;
        out[9 * nB + n]         = fiLap;
        out[10 * nB + n]        = jd;
    }
}

extern "C" void kernel_launch(void* const* d_in, const int* in_sizes, int n_in,
                              void* d_out, int out_size, void* d_ws, size_t ws_size,
                              hipStream_t stream) {
    const float* x  = (const float*)d_in[0];
    const float* W0 = (const float*)d_in[1];
    const float* b0 = (const float*)d_in[2];
    const float* W1 = (const float*)d_in[3];
    const float* b1 = (const float*)d_in[4];
    const float* W2 = (const float*)d_in[5];
    const float* b2 = (const float*)d_in[6];
    const float* W3 = (const float*)d_in[7];
    const float* b3 = (const float*)d_in[8];
    const float* Wo = (const float*)d_in[9];
    const float* bo = (const float*)d_in[10];
    float* out = (float*)d_out;
    u16*   Wt  = (u16*)d_ws;                 // 3*65536 + 512 bf16 ≈ 385 KB

    const int nB = in_sizes[0] / 4;          // 16384

    hipLaunchKernelGGL(prep_w, dim3(97), dim3(256), 0, stream, W1, W2, W3, Wo, Wt);
    hipLaunchKernelGGL(mlp_jet_mfma, dim3(nB / SPBM), dim3(256), 0, stream,
                       x, W0, b0, b1, b2, b3, bo, Wt, out, nB);
}

// Round 5
// 127.263 us; speedup vs baseline: 2.0049x; 2.0049x over previous
//
#include <hip/hip_runtime.h>

#define HDIM  256
#define YP    264              // padded Y row length in bf16 elems
#define SPBM  8                // samples per block
#define MROWS (SPBM * 8)       // 64 jet rows per block

typedef unsigned short u16;
typedef __attribute__((ext_vector_type(8))) short  short8;   // 8 bf16 (4 VGPRs)
typedef __attribute__((ext_vector_type(4))) float  f32x4;    // MFMA acc

// ---------------- Wt fragment layout (the round-5 change) ----------------
// B-fragment for mfma_f32_16x16x32_bf16: lane l holds B[n = t*16 + (l&15)]
// [k = ks*32 + (l>>4)*8 + j], j=0..7.  We store Wt so that one wave B-load
// is LANE-CONTIGUOUS (streaming, TA-friendly) instead of a 16-row gather:
//   elem offset within layer = ((t*8 + ks)*64 + l)*8 + j
// with t = n>>4 (0..15), ks = k>>5 (0..7), l = ((k>>3)&3)*16 + (n&15).
// Load: lane l reads 16B at  Wt_layer + (t*8+ks)*512*2B + l*16B  -> 1 KB/wave,
// 16 sequential 64B lines per load.
// -------------------------------------------------------------------------

// Row permutation (round-3 scheme): physical row R for (sample s, channel c):
//   R = 32*(s>>2) + 16*(c>>2) + 4*(s&3) + (c&3)
// => per MFMA C-tile pair (2h,2h+1), lane group g holds all 8 channels of
// sample 4h+g in registers -> per-lane jet epilogue, no shuffles.

__device__ __forceinline__ float bf2f(u16 u) {
    union { unsigned int i; float f; } v; v.i = ((unsigned int)u) << 16; return v.f;
}
// cheap round-half-up bf16 (2 VALU instr); fine vs 3% abs threshold
__device__ __forceinline__ u16 f2bf(float f) {
    union { float f; unsigned int u; } v; v.f = f;
    return (u16)((v.u + 0x8000u) >> 16);
}
// proper RNE, used once in prepass for weights
__device__ __forceinline__ u16 f2bf_rne(float f) {
    union { float f; unsigned int u; } v; v.f = f;
    unsigned int r = v.u + 0x7fffu + ((v.u >> 16) & 1u);
    return (u16)(r >> 16);
}
// tanh(x) = 1 - 2/(e^{2x}+1) on raw v_exp_f32 / v_rcp_f32 (~4 instr, NaN-free)
__device__ __forceinline__ float fast_tanh(float x) {
    const float e = __builtin_amdgcn_exp2f(x * 2.885390081777927f); // e^{2x}
    const float r = __builtin_amdgcn_rcpf(e + 1.f);
    return 1.f - 2.f * r;
}

// ---- prepass: W[k][n] f32 -> fragment-ordered bf16 Wt (W1,W2,W3),
// ---- plus Wo[k][2] -> Wob[2][256] bf16 at ws + 3*65536.
// 97 blocks; block = one (ks, 4 n-tiles) slab: 32 k x 64 n.
__global__ __launch_bounds__(256)
void prep_w(const float* __restrict__ W1, const float* __restrict__ W2,
            const float* __restrict__ W3, const float* __restrict__ Wo,
            u16* __restrict__ ws) {
    const int bid = blockIdx.x;
    const int tid = threadIdx.x;
    if (bid == 96) {
#pragma unroll
        for (int oc = 0; oc < 2; ++oc)
            ws[3 * 65536 + oc * 256 + tid] = f2bf_rne(Wo[tid * 2 + oc]);
        return;
    }
    const int which = bid >> 5;          // 0..2
    const int tile  = bid & 31;          // 8 k-slabs x 4 n-slabs
    const int k0 = (tile & 7) * 32;      // ks = tile & 7
    const int n0 = (tile >> 3) * 64;
    const float* W = (which == 0) ? W1 : ((which == 1) ? W2 : W3);
    __shared__ float T[32][65];
    const int rk = tid >> 4;             // 0..15
    const int rn = (tid & 15) * 4;       // 0..60
#pragma unroll
    for (int rep = 0; rep < 2; ++rep) {
        const float4 v = *(const float4*)(W + (k0 + rep * 16 + rk) * 256 + n0 + rn);
        T[rep * 16 + rk][rn + 0] = v.x;
        T[rep * 16 + rk][rn + 1] = v.y;
        T[rep * 16 + rk][rn + 2] = v.z;
        T[rep * 16 + rk][rn + 3] = v.w;
    }
    __syncthreads();
    // fragment-ordered write: thread -> (t_local = tid>>6, lane = tid&63)
    const int tl = tid >> 6;             // 0..3  (n-tile within slab)
    const int ln = tid & 63;             // fragment lane
    const int nn = tl * 16 + (ln & 15);          // n - n0
    const int kb = ((ln >> 4) & 3) * 8;          // k - k0 base
    short8 o;
#pragma unroll
    for (int j = 0; j < 8; ++j)
        o[j] = (short)f2bf_rne(T[kb + j][nn]);
    const int t_glob = (n0 >> 4) + tl;           // 0..15
    *(short8*)(ws + which * 65536 + ((t_glob * 8 + (tile & 7)) * 64 + ln) * 8) = o;
}

// ---- one hidden layer: Y(LDS, 64x256 bf16 jets) @ W(256x256) -> jets, in place ----
// 4 waves: wave wv owns all 64 rows x cols wv*64..+63.  acc[4][4] = 64 regs.
// C/D: col=lane&15, row=(lane>>4)*4+reg.  A: A[m=lane&15][k=8*(lane>>4)+j].
// B-loads are lane-contiguous 1KB streams (see layout comment above).
__device__ __forceinline__ void hidden_layer_mfma(u16* __restrict__ Y,
                                                  const u16* __restrict__ Wt,
                                                  const float* __restrict__ b,
                                                  int l, int wv) {
    const int lm    = l & 15;
    const int lk8   = (l >> 4) * 8;
    const int nbase = wv * 64;
    // per-lane fragment base: t = wv*4 + nt  ->  elem off = (t*8+ks)*512 + l*8
    const u16* bsrc = Wt + (wv * 4) * 4096 + l * 8;

    f32x4 acc[4][4];
#pragma unroll
    for (int mt = 0; mt < 4; ++mt)
#pragma unroll
        for (int nt = 0; nt < 4; ++nt) acc[mt][nt] = (f32x4){0.f, 0.f, 0.f, 0.f};

#pragma unroll
    for (int ks = 0; ks < 8; ++ks) {
        const int kk = ks * 32 + lk8;
        short8 a[4], bf[4];
#pragma unroll
        for (int mt = 0; mt < 4; ++mt)
            a[mt] = *(const short8*)(Y + (mt * 16 + lm) * YP + kk);
#pragma unroll
        for (int nt = 0; nt < 4; ++nt)
            bf[nt] = *(const short8*)(bsrc + nt * 4096 + ks * 512);
#pragma unroll
        for (int mt = 0; mt < 4; ++mt)
#pragma unroll
            for (int nt = 0; nt < 4; ++nt)
                acc[mt][nt] = __builtin_amdgcn_mfma_f32_16x16x32_bf16(
                    a[mt], bf[nt], acc[mt][nt], 0, 0, 0);
    }

    float bias[4];
#pragma unroll
    for (int nt = 0; nt < 4; ++nt) bias[nt] = b[nbase + nt * 16 + lm];

    __syncthreads();   // all waves done READING Y before anyone overwrites it

    const int g = l >> 4;    // sample-in-group 0..3
#pragma unroll
    for (int half = 0; half < 2; ++half) {      // samples 4*half+g
#pragma unroll
        for (int nt = 0; nt < 4; ++nt) {
            const f32x4 ulo = acc[2 * half + 0][nt];   // v,g0,g1,g2 preacts
            const f32x4 uhi = acc[2 * half + 1][nt];   // g3,s0,s1,s2 preacts
            const float ty = fast_tanh(ulo[0] + bias[nt]);
            const float t  = 1.f - ty * ty;
            const float m  = -2.f * ty * t;
            const int n = nbase + nt * 16 + lm;
            u16* ylo = Y + (half * 32 + 4 * g) * YP + n;
            u16* yhi = ylo + 16 * YP;
            ylo[0 * YP] = f2bf(ty);
            ylo[1 * YP] = f2bf(t * ulo[1]);
            ylo[2 * YP] = f2bf(t * ulo[2]);
            ylo[3 * YP] = f2bf(t * ulo[3]);
            yhi[0 * YP] = f2bf(t * uhi[0]);
            yhi[1 * YP] = f2bf(t * uhi[1] + m * ulo[1] * ulo[1]);
            yhi[2 * YP] = f2bf(t * uhi[2] + m * ulo[2] * ulo[2]);
            yhi[3 * YP] = f2bf(t * uhi[3] + m * ulo[3] * ulo[3]);
        }
    }
    __syncthreads();
}

__global__ __launch_bounds__(256, 4)
void mlp_jet_mfma(const float* __restrict__ x,
                  const float* __restrict__ W0, const float* __restrict__ b0,
                  const float* __restrict__ b1, const float* __restrict__ b2,
                  const float* __restrict__ b3, const float* __restrict__ bo,
                  const u16* __restrict__ Wt,   // 3 x fragment-ordered Wt, + Wob[2][256]
                  float* __restrict__ out, int nB) {
    __shared__ __align__(16) u16 Y[MROWS * YP];
    __shared__ float4 xs4[SPBM];
    __shared__ float  part[MROWS][2];

    const int tid = threadIdx.x;
    const int wv  = tid >> 6;            // 0..3
    const int l   = tid & 63;
    const int lm  = l & 15;
    const int lk8 = (l >> 4) * 8;
    const int n0  = blockIdx.x * SPBM;

    // ---- layer 0: 4 -> 256, VALU ----
    if (tid < SPBM) xs4[tid] = *(const float4*)(x + (n0 + tid) * 4);
    __syncthreads();
    {
        const int n = tid;
        const float w0 = W0[0 * HDIM + n], w1 = W0[1 * HDIM + n];
        const float w2 = W0[2 * HDIM + n], w3 = W0[3 * HDIM + n];
        const float bb = b0[n];
#pragma unroll
        for (int s = 0; s < SPBM; ++s) {
            const float4 xv = xs4[s];
            const float u  = xv.x * w0 + xv.y * w1 + xv.z * w2 + xv.w * w3 + bb;
            const float ty = fast_tanh(u);
            const float t  = 1.f - ty * ty;
            const float m  = -2.f * ty * t;
            // permuted rows: base = 32*(s>>2) + 4*(s&3); ch0..3 there, ch4..7 at +16
            u16* ylo = Y + (32 * (s >> 2) + 4 * (s & 3)) * YP + n;
            u16* yhi = ylo + 16 * YP;
            ylo[0 * YP] = f2bf(ty);
            ylo[1 * YP] = f2bf(t * w0);
            ylo[2 * YP] = f2bf(t * w1);
            ylo[3 * YP] = f2bf(t * w2);
            yhi[0 * YP] = f2bf(t * w3);
            yhi[1 * YP] = f2bf(m * w0 * w0);
            yhi[2 * YP] = f2bf(m * w1 * w1);
            yhi[3 * YP] = f2bf(m * w2 * w2);
        }
    }
    __syncthreads();

    // ---- 3 hidden layers on the matrix pipe ----
    hidden_layer_mfma(Y, Wt + 0 * 65536, b1, l, wv);
    hidden_layer_mfma(Y, Wt + 1 * 65536, b2, l, wv);
    hidden_layer_mfma(Y, Wt + 2 * 65536, b3, l, wv);

    // ---- output head on MFMA: wave wv takes physical rows wv*16..wv*16+15 ----
    {
        const u16* wob = Wt + 3 * 65536;
        f32x4 h = (f32x4){0.f, 0.f, 0.f, 0.f};
#pragma unroll
        for (int ks = 0; ks < 8; ++ks) {
            const int kk = ks * 32 + lk8;
            const short8 a = *(const short8*)(Y + (wv * 16 + lm) * YP + kk);
            short8 bfr = (short8){0,0,0,0,0,0,0,0};
            if (lm < 2) bfr = *(const short8*)(wob + lm * 256 + kk);
            h = __builtin_amdgcn_mfma_f32_16x16x32_bf16(a, bfr, h, 0, 0, 0);
        }
        if (lm < 2) {
#pragma unroll
            for (int r = 0; r < 4; ++r)
                part[wv * 16 + (l >> 4) * 4 + r][lm] = h[r];
        }
    }
    __syncthreads();

    if (tid < SPBM) {
        const int s = tid;
        float q0[8], q1[8];
#pragma unroll
        for (int ch = 0; ch < 8; ++ch) {
            const int R = 32 * (s >> 2) + 16 * (ch >> 2) + 4 * (s & 3) + (ch & 3);
            q0[ch] = part[R][0];
            q1[ch] = part[R][1];
        }
        const float c0  = q0[0] + bo[0];
        const float Fi  = q1[0] + bo[1];
        const float cg0 = q0[1], cg1 = q0[2], cg2 = q0[3];
        const float ct  = q0[4];                 // dc/dx_3 (TDIM)
        const float fg0 = q1[1], fg1 = q1[2], fg2 = q1[3];
        const float trHc  = q0[5] + q0[6] + q0[7];
        const float fiLap = q1[5] + q1[6] + q1[7];
        const float jd = -trHc
                         - (cg0 * fg0 + cg1 * fg1 + cg2 * fg2 + c0 * fiLap)
                         + 0.1f * (cg0 + cg1 + cg2);
        const int n = n0 + s;
        out[0 * nB + n]         = c0;
        out[1 * nB + n]         = ct;
        out[2 * nB + 3 * n + 0] = cg0;
        out[2 * nB + 3 * n + 1] = cg1;
        out[2 * nB + 3 * n + 2] = cg2;
        out[5 * nB + n]         = Fi;
        out[6 * nB + 3 * n + 0] = fg0;
        out[6 * nB + 3 * n + 1] = fg1;
        out[6 * nB + 3 * n + 2] = fg2;
        out[9 * nB + n]         = fiLap;
        out[10 * nB + n]        = jd;
    }
}

extern "C" void kernel_launch(void* const* d_in, const int* in_sizes, int n_in,
                              void* d_out, int out_size, void* d_ws, size_t ws_size,
                              hipStream_t stream) {
    const float* x  = (const float*)d_in[0];
    const float* W0 = (const float*)d_in[1];
    const float* b0 = (const float*)d_in[2];
    const float* W1 = (const float*)d_in[3];
    const float* b1 = (const float*)d_in[4];
    const float* W2 = (const float*)d_in[5];
    const float* b2 = (const float*)d_in[6];
    const float* W3 = (const float*)d_in[7];
    const float* b3 = (const float*)d_in[8];
    const float* Wo = (const float*)d_in[9];
    const float* bo = (const float*)d_in[10];
    float* out = (float*)d_out;
    u16*   Wt  = (u16*)d_ws;                 // 3*65536 + 512 bf16 ≈ 385 KB

    const int nB = in_sizes[0] / 4;          // 16384

    hipLaunchKernelGGL(prep_w, dim3(97), dim3(256), 0, stream, W1, W2, W3, Wo, Wt);
    hipLaunchKernelGGL(mlp_jet_mfma, dim3(nB / SPBM), dim3(256), 0, stream,
                       x, W0, b0, b1, b2, b3, bo, Wt, out, nB);
}

// Round 6
// 126.613 us; speedup vs baseline: 2.0152x; 1.0051x over previous
//
#include <hip/hip_runtime.h>

#define HDIM  256
#define YP    264              // padded Y row length in bf16 elems
#define SPBM  8                // samples per block
#define MROWS (SPBM * 8)       // 64 jet rows per block

typedef unsigned short u16;
typedef __attribute__((ext_vector_type(8))) short  short8;   // 8 bf16 (4 VGPRs)
typedef __attribute__((ext_vector_type(4))) float  f32x4;    // MFMA acc

// ---------------- Wt fragment layout + COLUMN PERMUTATION (round 6) -------
// B-fragment for mfma_f32_16x16x32_bf16: lane l supplies B[k][tile-col l&15].
// Fragment-ordered storage (round 5): one wave B-load is lane-contiguous 1KB.
// NEW: tile-col -> logical-n mapping is PERMUTED:  tile t, tile-col m holds
// logical n = (t>>2)*64 + 4*m + (t&3).
// Consequence: lane lm's four nt-accumulators are logical cols 4*lm+0..3 of
// the wave's quarter -> epilogue packs 4 bf16 and writes ONE ds_write_b64
// per row instead of 4 scalar u16 writes.  Y itself stays in logical order,
// so A-reads / head / biases are untouched (bias becomes one float4).
// -------------------------------------------------------------------------

// Row permutation (round-3 scheme): physical row R for (sample s, channel c):
//   R = 32*(s>>2) + 16*(c>>2) + 4*(s&3) + (c&3)
// => per MFMA C-tile pair (2h,2h+1), lane group g holds all 8 channels of
// sample 4h+g in registers -> per-lane jet epilogue, no shuffles.

// proper RNE, used once in prepass for weights
__device__ __forceinline__ u16 f2bf_rne(float f) {
    union { float f; unsigned int u; } v; v.f = f;
    unsigned int r = v.u + 0x7fffu + ((v.u >> 16) & 1u);
    return (u16)(r >> 16);
}
// pack two floats to bf16 pair (round-half-up; fine vs 3% abs threshold)
__device__ __forceinline__ unsigned int pk2(float a, float b) {
    union { float f; unsigned int u; } x, y; x.f = a; y.f = b;
    return ((x.u + 0x8000u) >> 16) | ((y.u + 0x8000u) & 0xFFFF0000u);
}
// tanh(x) = 1 - 2/(e^{2x}+1) on raw v_exp_f32 / v_rcp_f32 (~4 instr, NaN-free)
__device__ __forceinline__ float fast_tanh(float x) {
    const float e = __builtin_amdgcn_exp2f(x * 2.885390081777927f); // e^{2x}
    const float r = __builtin_amdgcn_rcpf(e + 1.f);
    return 1.f - 2.f * r;
}

// ---- prepass: W[k][n] f32 -> fragment-ordered, column-permuted bf16 Wt
// ---- (W1,W2,W3), plus Wo[k][2] -> Wob[2][256] bf16 at ws + 3*65536.
// 97 blocks; block = one (ks, 4 n-tiles) slab: 32 k x 64 n.
__global__ __launch_bounds__(256)
void prep_w(const float* __restrict__ W1, const float* __restrict__ W2,
            const float* __restrict__ W3, const float* __restrict__ Wo,
            u16* __restrict__ ws) {
    const int bid = blockIdx.x;
    const int tid = threadIdx.x;
    if (bid == 96) {
#pragma unroll
        for (int oc = 0; oc < 2; ++oc)
            ws[3 * 65536 + oc * 256 + tid] = f2bf_rne(Wo[tid * 2 + oc]);
        return;
    }
    const int which = bid >> 5;          // 0..2
    const int tile  = bid & 31;          // 8 k-slabs x 4 n-slabs
    const int k0 = (tile & 7) * 32;      // ks = tile & 7
    const int n0 = (tile >> 3) * 64;
    const float* W = (which == 0) ? W1 : ((which == 1) ? W2 : W3);
    __shared__ float T[32][65];
    const int rk = tid >> 4;             // 0..15
    const int rn = (tid & 15) * 4;       // 0..60
#pragma unroll
    for (int rep = 0; rep < 2; ++rep) {
        const float4 v = *(const float4*)(W + (k0 + rep * 16 + rk) * 256 + n0 + rn);
        T[rep * 16 + rk][rn + 0] = v.x;
        T[rep * 16 + rk][rn + 1] = v.y;
        T[rep * 16 + rk][rn + 2] = v.z;
        T[rep * 16 + rk][rn + 3] = v.w;
    }
    __syncthreads();
    // fragment-ordered write: thread -> (t_local = tid>>6, lane = tid&63)
    const int tl = tid >> 6;             // 0..3  (n-tile within slab, = t&3)
    const int ln = tid & 63;             // fragment lane
    const int nn = 4 * (ln & 15) + tl;           // PERMUTED logical n - n0
    const int kb = ((ln >> 4) & 3) * 8;          // k - k0 base
    short8 o;
#pragma unroll
    for (int j = 0; j < 8; ++j)
        o[j] = (short)f2bf_rne(T[kb + j][nn]);
    const int t_glob = (n0 >> 4) + tl;           // 0..15
    *(short8*)(ws + which * 65536 + ((t_glob * 8 + (tile & 7)) * 64 + ln) * 8) = o;
}

// ---- one hidden layer: Y(LDS, 64x256 bf16 jets) @ W(256x256) -> jets, in place ----
// 4 waves: wave wv owns all 64 rows x cols wv*64..+63.  acc[4][4] = 64 regs.
// C/D: col=lane&15, row=(lane>>4)*4+reg.  A: A[m=lane&15][k=8*(lane>>4)+j].
// B-loads lane-contiguous 1KB streams; B cols permuted so lane lm's nt=0..3
// accs are logical cols 4*lm..4*lm+3 -> epilogue writes ds_write_b64 per row.
__device__ __forceinline__ void hidden_layer_mfma(u16* __restrict__ Y,
                                                  const u16* __restrict__ Wt,
                                                  const float* __restrict__ b,
                                                  int l, int wv) {
    const int lm    = l & 15;
    const int lk8   = (l >> 4) * 8;
    const int nbase = wv * 64;
    // per-lane fragment base: t = wv*4 + nt  ->  elem off = (t*8+ks)*512 + l*8
    const u16* bsrc = Wt + (wv * 4) * 4096 + l * 8;

    f32x4 acc[4][4];
#pragma unroll
    for (int mt = 0; mt < 4; ++mt)
#pragma unroll
        for (int nt = 0; nt < 4; ++nt) acc[mt][nt] = (f32x4){0.f, 0.f, 0.f, 0.f};

#pragma unroll
    for (int ks = 0; ks < 8; ++ks) {
        const int kk = ks * 32 + lk8;
        short8 a[4], bf[4];
#pragma unroll
        for (int mt = 0; mt < 4; ++mt)
            a[mt] = *(const short8*)(Y + (mt * 16 + lm) * YP + kk);
#pragma unroll
        for (int nt = 0; nt < 4; ++nt)
            bf[nt] = *(const short8*)(bsrc + nt * 4096 + ks * 512);
#pragma unroll
        for (int mt = 0; mt < 4; ++mt)
#pragma unroll
            for (int nt = 0; nt < 4; ++nt)
                acc[mt][nt] = __builtin_amdgcn_mfma_f32_16x16x32_bf16(
                    a[mt], bf[nt], acc[mt][nt], 0, 0, 0);
    }

    // bias for logical cols nbase + 4*lm + 0..3  (one float4)
    const float4 b4 = *(const float4*)(b + nbase + 4 * lm);
    const float ba[4] = {b4.x, b4.y, b4.z, b4.w};

    __syncthreads();   // all waves done READING Y before anyone overwrites it

    const int g = l >> 4;    // sample-in-group 0..3
#pragma unroll
    for (int half = 0; half < 2; ++half) {      // samples 4*half+g
        float ty[4], tt[4], mm[4];
#pragma unroll
        for (int nt = 0; nt < 4; ++nt) {
            ty[nt] = fast_tanh(acc[2 * half][nt][0] + ba[nt]);
            tt[nt] = 1.f - ty[nt] * ty[nt];
            mm[nt] = -2.f * ty[nt] * tt[nt];
        }
        u16* yrow = Y + (half * 32 + 4 * g) * YP + nbase + 4 * lm;
        {   // j = 0 rows: channel v (lo) | channel g3 (hi)
            uint2 wlo, whi;
            wlo.x = pk2(ty[0], ty[1]);
            wlo.y = pk2(ty[2], ty[3]);
            whi.x = pk2(tt[0] * acc[2 * half + 1][0][0], tt[1] * acc[2 * half + 1][1][0]);
            whi.y = pk2(tt[2] * acc[2 * half + 1][2][0], tt[3] * acc[2 * half + 1][3][0]);
            *(uint2*)(yrow)           = wlo;
            *(uint2*)(yrow + 16 * YP) = whi;
        }
#pragma unroll
        for (int j = 1; j < 4; ++j) {   // rows: g_{j-1} (lo) | s_{j-1} (hi)
            float lo[4], hi[4];
#pragma unroll
            for (int nt = 0; nt < 4; ++nt) {
                const float a = acc[2 * half][nt][j];
                lo[nt] = tt[nt] * a;
                hi[nt] = tt[nt] * acc[2 * half + 1][nt][j] + mm[nt] * a * a;
            }
            uint2 wlo, whi;
            wlo.x = pk2(lo[0], lo[1]);  wlo.y = pk2(lo[2], lo[3]);
            whi.x = pk2(hi[0], hi[1]);  whi.y = pk2(hi[2], hi[3]);
            *(uint2*)(yrow + j * YP)        = wlo;
            *(uint2*)(yrow + (16 + j) * YP) = whi;
        }
    }
    __syncthreads();
}

__global__ __launch_bounds__(256, 4)
void mlp_jet_mfma(const float* __restrict__ x,
                  const float* __restrict__ W0, const float* __restrict__ b0,
                  const float* __restrict__ b1, const float* __restrict__ b2,
                  const float* __restrict__ b3, const float* __restrict__ bo,
                  const u16* __restrict__ Wt,   // 3 x fragment-ordered Wt, + Wob[2][256]
                  float* __restrict__ out, int nB) {
    __shared__ __align__(16) u16 Y[MROWS * YP];
    __shared__ float4 xs4[SPBM];
    __shared__ float  part[MROWS][2];

    const int tid = threadIdx.x;
    const int wv  = tid >> 6;            // 0..3
    const int l   = tid & 63;
    const int lm  = l & 15;
    const int lk8 = (l >> 4) * 8;
    const int n0  = blockIdx.x * SPBM;

    // ---- layer 0: 4 -> 256, VALU; thread -> (sample, 4-col group), b64 writes ----
    if (tid < SPBM) xs4[tid] = *(const float4*)(x + (n0 + tid) * 4);
    __syncthreads();
#pragma unroll
    for (int rep = 0; rep < 2; ++rep) {
        const int idx = tid + 256 * rep;         // 0..511
        const int s   = idx >> 6;                // sample 0..7 (uniform per wave)
        const int cg  = idx & 63;                // 4-col group
        const float4 xv  = xs4[s];
        const float4 w0v = *(const float4*)(W0 + 0 * HDIM + 4 * cg);
        const float4 w1v = *(const float4*)(W0 + 1 * HDIM + 4 * cg);
        const float4 w2v = *(const float4*)(W0 + 2 * HDIM + 4 * cg);
        const float4 w3v = *(const float4*)(W0 + 3 * HDIM + 4 * cg);
        const float4 bbv = *(const float4*)(b0 + 4 * cg);
        const float w0a[4] = {w0v.x, w0v.y, w0v.z, w0v.w};
        const float w1a[4] = {w1v.x, w1v.y, w1v.z, w1v.w};
        const float w2a[4] = {w2v.x, w2v.y, w2v.z, w2v.w};
        const float w3a[4] = {w3v.x, w3v.y, w3v.z, w3v.w};
        const float bba[4] = {bbv.x, bbv.y, bbv.z, bbv.w};
        float ty[4], tt[4], mm[4];
#pragma unroll
        for (int c = 0; c < 4; ++c) {
            const float u = xv.x * w0a[c] + xv.y * w1a[c] + xv.z * w2a[c]
                          + xv.w * w3a[c] + bba[c];
            ty[c] = fast_tanh(u);
            tt[c] = 1.f - ty[c] * ty[c];
            mm[c] = -2.f * ty[c] * tt[c];
        }
        // permuted rows: ch0..3 at R.., ch4..7 at R+16..;  R = 32*(s>>2)+4*(s&3)
        u16* yr = Y + (32 * (s >> 2) + 4 * (s & 3)) * YP + 4 * cg;
        uint2 v;
        v.x = pk2(ty[0], ty[1]);             v.y = pk2(ty[2], ty[3]);
        *(uint2*)(yr + 0 * YP) = v;                          // ch0: tanh
        v.x = pk2(tt[0]*w0a[0], tt[1]*w0a[1]); v.y = pk2(tt[2]*w0a[2], tt[3]*w0a[3]);
        *(uint2*)(yr + 1 * YP) = v;                          // ch1: t*w0
        v.x = pk2(tt[0]*w1a[0], tt[1]*w1a[1]); v.y = pk2(tt[2]*w1a[2], tt[3]*w1a[3]);
        *(uint2*)(yr + 2 * YP) = v;                          // ch2: t*w1
        v.x = pk2(tt[0]*w2a[0], tt[1]*w2a[1]); v.y = pk2(tt[2]*w2a[2], tt[3]*w2a[3]);
        *(uint2*)(yr + 3 * YP) = v;                          // ch3: t*w2
        v.x = pk2(tt[0]*w3a[0], tt[1]*w3a[1]); v.y = pk2(tt[2]*w3a[2], tt[3]*w3a[3]);
        *(uint2*)(yr + 16 * YP) = v;                         // ch4: t*w3
        v.x = pk2(mm[0]*w0a[0]*w0a[0], mm[1]*w0a[1]*w0a[1]);
        v.y = pk2(mm[2]*w0a[2]*w0a[2], mm[3]*w0a[3]*w0a[3]);
        *(uint2*)(yr + 17 * YP) = v;                         // ch5: m*w0^2
        v.x = pk2(mm[0]*w1a[0]*w1a[0], mm[1]*w1a[1]*w1a[1]);
        v.y = pk2(mm[2]*w1a[2]*w1a[2], mm[3]*w1a[3]*w1a[3]);
        *(uint2*)(yr + 18 * YP) = v;                         // ch6: m*w1^2
        v.x = pk2(mm[0]*w2a[0]*w2a[0], mm[1]*w2a[1]*w2a[1]);
        v.y = pk2(mm[2]*w2a[2]*w2a[2], mm[3]*w2a[3]*w2a[3]);
        *(uint2*)(yr + 19 * YP) = v;                         // ch7: m*w2^2
    }
    __syncthreads();

    // ---- 3 hidden layers on the matrix pipe ----
    hidden_layer_mfma(Y, Wt + 0 * 65536, b1, l, wv);
    hidden_layer_mfma(Y, Wt + 1 * 65536, b2, l, wv);
    hidden_layer_mfma(Y, Wt + 2 * 65536, b3, l, wv);

    // ---- output head on MFMA: wave wv takes physical rows wv*16..wv*16+15 ----
    {
        const u16* wob = Wt + 3 * 65536;
        f32x4 h = (f32x4){0.f, 0.f, 0.f, 0.f};
#pragma unroll
        for (int ks = 0; ks < 8; ++ks) {
            const int kk = ks * 32 + lk8;
            const short8 a = *(const short8*)(Y + (wv * 16 + lm) * YP + kk);
            short8 bfr = (short8){0,0,0,0,0,0,0,0};
            if (lm < 2) bfr = *(const short8*)(wob + lm * 256 + kk);
            h = __builtin_amdgcn_mfma_f32_16x16x32_bf16(a, bfr, h, 0, 0, 0);
        }
        if (lm < 2) {
#pragma unroll
            for (int r = 0; r < 4; ++r)
                part[wv * 16 + (l >> 4) * 4 + r][lm] = h[r];
        }
    }
    __syncthreads();

    if (tid < SPBM) {
        const int s = tid;
        float q0[8], q1[8];
#pragma unroll
        for (int ch = 0; ch < 8; ++ch) {
            const int R = 32 * (s >> 2) + 16 * (ch >> 2) + 4 * (s & 3) + (ch & 3);
            q0[ch] = part[R][0];
            q1[ch] = part[R][1];
        }
        const float c0  = q0[0] + bo[0];
        const float Fi  = q1[0] + bo[1];
        const float cg0 = q0[1], cg1 = q0[2], cg2 = q0[3];
        const float ct  = q0[4];                 // dc/dx_3 (TDIM)
        const float fg0 = q1[1], fg1 = q1[2], fg2 = q1[3];
        const float trHc  = q0[5] + q0[6] + q0[7];
        const float fiLap = q1[5] + q1[6] + q1[7];
        const float jd = -trHc
                         - (cg0 * fg0 + cg1 * fg1 + cg2 * fg2 + c0 * fiLap)
                         + 0.1f * (cg0 + cg1 + cg2);
        const int n = n0 + s;
        out[0 * nB + n]         = c0;
        out[1 * nB + n]         = ct;
        out[2 * nB + 3 * n + 0] = cg0;
        out[2 * nB + 3 * n + 1] = cg1;
        out[2 * nB + 3 * n + 2] = cg2;
        out[5 * nB + n]         = Fi;
        out[6 * nB + 3 * n + 0] = fg0;
        out[6 * nB + 3 * n + 1] = fg1;
        out[6 * nB + 3 * n + 2] = fg2;
        out[9 * nB + n]         = fiLap;
        out[10 * nB + n]        = jd;
    }
}

extern "C" void kernel_launch(void* const* d_in, const int* in_sizes, int n_in,
                              void* d_out, int out_size, void* d_ws, size_t ws_size,
                              hipStream_t stream) {
    const float* x  = (const float*)d_in[0];
    const float* W0 = (const float*)d_in[1];
    const float* b0 = (const float*)d_in[2];
    const float* W1 = (const float*)d_in[3];
    const float* b1 = (const float*)d_in[4];
    const float* W2 = (const float*)d_in[5];
    const float* b2 = (const float*)d_in[6];
    const float* W3 = (const float*)d_in[7];
    const float* b3 = (const float*)d_in[8];
    const float* Wo = (const float*)d_in[9];
    const float* bo = (const float*)d_in[10];
    float* out = (float*)d_out;
    u16*   Wt  = (u16*)d_ws;                 // 3*65536 + 512 bf16 ≈ 385 KB

    const int nB = in_sizes[0] / 4;          // 16384

    hipLaunchKernelGGL(prep_w, dim3(97), dim3(256), 0, stream, W1, W2, W3, Wo, Wt);
    hipLaunchKernelGGL(mlp_jet_mfma, dim3(nB / SPBM), dim3(256), 0, stream,
                       x, W0, b0, b1, b2, b3, bo, Wt, out, nB);
}

// Round 7
// 124.218 us; speedup vs baseline: 2.0540x; 1.0193x over previous
//
#include <hip/hip_runtime.h>

#define HDIM  256
#define YP    264              // padded Y row length in bf16 elems
#define SPBM  8                // samples per block
#define MROWS (SPBM * 8)       // 64 jet rows per block

typedef unsigned short u16;
typedef __attribute__((ext_vector_type(8))) short  short8;   // 8 bf16 (4 VGPRs)
typedef __attribute__((ext_vector_type(4))) float  f32x4;    // MFMA acc

// ---------------- Wt fragment layout + column permutation (r5/r6) ---------
// B-fragment storage is lane-contiguous (1KB streaming loads per wave), and
// tile-col -> logical-n mapping is permuted:  tile t, tile-col m holds
// logical n = (t>>2)*64 + 4*m + (t&3).  So lane lm's four nt-accumulators
// are logical cols 4*lm..4*lm+3 -> epilogue writes ds_write_b64 per row.
// Row permutation (r3): physical row R for (sample s, channel c):
//   R = 32*(s>>2) + 16*(c>>2) + 4*(s&3) + (c&3)
// => per C-tile pair lane group g holds all 8 channels of sample 4h+g
// in registers -> per-lane jet epilogue, no shuffles.
// Round 7: nt-PAIR epilogue with static pk[2][8] packing + v_cvt_pk_bf16_f32
// (1 instr, RNE) to keep live regs < 128 and avoid the r6 scratch spill.
// -------------------------------------------------------------------------

// proper RNE, used once in prepass for weights
__device__ __forceinline__ u16 f2bf_rne(float f) {
    union { float f; unsigned int u; } v; v.f = f;
    unsigned int r = v.u + 0x7fffu + ((v.u >> 16) & 1u);
    return (u16)(r >> 16);
}
// pack two f32 -> bf16x2 in one VALU instr (RNE)
__device__ __forceinline__ unsigned int cvtpk(float a, float b) {
    unsigned int r;
    asm("v_cvt_pk_bf16_f32 %0, %1, %2" : "=v"(r) : "v"(a), "v"(b));
    return r;
}
// tanh(x) = 1 - 2/(e^{2x}+1) on raw v_exp_f32 / v_rcp_f32 (~4 instr, NaN-free)
__device__ __forceinline__ float fast_tanh(float x) {
    const float e = __builtin_amdgcn_exp2f(x * 2.885390081777927f); // e^{2x}
    const float r = __builtin_amdgcn_rcpf(e + 1.f);
    return 1.f - 2.f * r;
}

// ---- prepass: W[k][n] f32 -> fragment-ordered, column-permuted bf16 Wt
// ---- (W1,W2,W3), plus Wo[k][2] -> Wob[2][256] bf16 at ws + 3*65536.
// 97 blocks; block = one (ks, 4 n-tiles) slab: 32 k x 64 n.
__global__ __launch_bounds__(256)
void prep_w(const float* __restrict__ W1, const float* __restrict__ W2,
            const float* __restrict__ W3, const float* __restrict__ Wo,
            u16* __restrict__ ws) {
    const int bid = blockIdx.x;
    const int tid = threadIdx.x;
    if (bid == 96) {
#pragma unroll
        for (int oc = 0; oc < 2; ++oc)
            ws[3 * 65536 + oc * 256 + tid] = f2bf_rne(Wo[tid * 2 + oc]);
        return;
    }
    const int which = bid >> 5;          // 0..2
    const int tile  = bid & 31;          // 8 k-slabs x 4 n-slabs
    const int k0 = (tile & 7) * 32;      // ks = tile & 7
    const int n0 = (tile >> 3) * 64;
    const float* W = (which == 0) ? W1 : ((which == 1) ? W2 : W3);
    __shared__ float T[32][65];
    const int rk = tid >> 4;             // 0..15
    const int rn = (tid & 15) * 4;       // 0..60
#pragma unroll
    for (int rep = 0; rep < 2; ++rep) {
        const float4 v = *(const float4*)(W + (k0 + rep * 16 + rk) * 256 + n0 + rn);
        T[rep * 16 + rk][rn + 0] = v.x;
        T[rep * 16 + rk][rn + 1] = v.y;
        T[rep * 16 + rk][rn + 2] = v.z;
        T[rep * 16 + rk][rn + 3] = v.w;
    }
    __syncthreads();
    // fragment-ordered write: thread -> (t_local = tid>>6, lane = tid&63)
    const int tl = tid >> 6;             // 0..3  (n-tile within slab, = t&3)
    const int ln = tid & 63;             // fragment lane
    const int nn = 4 * (ln & 15) + tl;           // PERMUTED logical n - n0
    const int kb = ((ln >> 4) & 3) * 8;          // k - k0 base
    short8 o;
#pragma unroll
    for (int j = 0; j < 8; ++j)
        o[j] = (short)f2bf_rne(T[kb + j][nn]);
    const int t_glob = (n0 >> 4) + tl;           // 0..15
    *(short8*)(ws + which * 65536 + ((t_glob * 8 + (tile & 7)) * 64 + ln) * 8) = o;
}

// ---- one hidden layer: Y(LDS, 64x256 bf16 jets) @ W(256x256) -> jets, in place ----
// 4 waves: wave wv owns all 64 rows x cols wv*64..+63.  acc[4][4] = 64 regs.
// C/D: col=lane&15, row=(lane>>4)*4+reg.  A: A[m=lane&15][k=8*(lane>>4)+j].
// B-loads lane-contiguous 1KB streams; B cols permuted (see header comment).
__device__ __forceinline__ void hidden_layer_mfma(u16* __restrict__ Y,
                                                  const u16* __restrict__ Wt,
                                                  const float* __restrict__ b,
                                                  int l, int wv) {
    const int lm    = l & 15;
    const int lk8   = (l >> 4) * 8;
    const int nbase = wv * 64;
    // per-lane fragment base: t = wv*4 + nt  ->  elem off = (t*8+ks)*512 + l*8
    const u16* bsrc = Wt + (wv * 4) * 4096 + l * 8;

    f32x4 acc[4][4];
#pragma unroll
    for (int mt = 0; mt < 4; ++mt)
#pragma unroll
        for (int nt = 0; nt < 4; ++nt) acc[mt][nt] = (f32x4){0.f, 0.f, 0.f, 0.f};

#pragma unroll
    for (int ks = 0; ks < 8; ++ks) {
        const int kk = ks * 32 + lk8;
        short8 a[4], bf[4];
#pragma unroll
        for (int mt = 0; mt < 4; ++mt)
            a[mt] = *(const short8*)(Y + (mt * 16 + lm) * YP + kk);
#pragma unroll
        for (int nt = 0; nt < 4; ++nt)
            bf[nt] = *(const short8*)(bsrc + nt * 4096 + ks * 512);
#pragma unroll
        for (int mt = 0; mt < 4; ++mt)
#pragma unroll
            for (int nt = 0; nt < 4; ++nt)
                acc[mt][nt] = __builtin_amdgcn_mfma_f32_16x16x32_bf16(
                    a[mt], bf[nt], acc[mt][nt], 0, 0, 0);
    }

    // bias for logical cols nbase + 4*lm + 0..3  (one float4)
    const float4 b4 = *(const float4*)(b + nbase + 4 * lm);

    __syncthreads();   // all waves done READING Y before anyone overwrites it

    const int g = l >> 4;    // sample-in-group 0..3
#pragma unroll
    for (int half = 0; half < 2; ++half) {      // samples 4*half+g
        // pk[pr][row]: pr = nt-pair (cols 4lm+2pr, +1); rows 0..3 = ch0..3,
        // rows 4..7 = ch4..7.  All indices compile-time -> registers.
        unsigned int pk[2][8];
#pragma unroll
        for (int pr = 0; pr < 2; ++pr) {
            const int na = 2 * pr, nb = 2 * pr + 1;
            const float bba = (pr == 0) ? b4.x : b4.z;
            const float bbb = (pr == 0) ? b4.y : b4.w;
            const float ty0 = fast_tanh(acc[2 * half][na][0] + bba);
            const float ty1 = fast_tanh(acc[2 * half][nb][0] + bbb);
            const float t0 = 1.f - ty0 * ty0, t1 = 1.f - ty1 * ty1;
            const float m0 = -2.f * ty0 * t0, m1 = -2.f * ty1 * t1;
            pk[pr][0] = cvtpk(ty0, ty1);
            pk[pr][4] = cvtpk(t0 * acc[2 * half + 1][na][0],
                              t1 * acc[2 * half + 1][nb][0]);
#pragma unroll
            for (int j = 1; j < 4; ++j) {
                const float a0 = acc[2 * half][na][j];
                const float a1 = acc[2 * half][nb][j];
                pk[pr][j]     = cvtpk(t0 * a0, t1 * a1);
                pk[pr][4 + j] = cvtpk(t0 * acc[2 * half + 1][na][j] + m0 * a0 * a0,
                                      t1 * acc[2 * half + 1][nb][j] + m1 * a1 * a1);
            }
        }
        u16* yrow = Y + (half * 32 + 4 * g) * YP + nbase + 4 * lm;
#pragma unroll
        for (int j = 0; j < 4; ++j) {
            *(uint2*)(yrow + j * YP)        = (uint2){pk[0][j],     pk[1][j]};
            *(uint2*)(yrow + (16 + j) * YP) = (uint2){pk[0][4 + j], pk[1][4 + j]};
        }
    }
    __syncthreads();
}

__global__ __launch_bounds__(256, 4)
void mlp_jet_mfma(const float* __restrict__ x,
                  const float* __restrict__ W0, const float* __restrict__ b0,
                  const float* __restrict__ b1, const float* __restrict__ b2,
                  const float* __restrict__ b3, const float* __restrict__ bo,
                  const u16* __restrict__ Wt,   // 3 x fragment-ordered Wt, + Wob[2][256]
                  float* __restrict__ out, int nB) {
    __shared__ __align__(16) u16 Y[MROWS * YP];
    __shared__ float4 xs4[SPBM];
    __shared__ float  part[MROWS][2];

    const int tid = threadIdx.x;
    const int wv  = tid >> 6;            // 0..3
    const int l   = tid & 63;
    const int lm  = l & 15;
    const int lk8 = (l >> 4) * 8;
    const int n0  = blockIdx.x * SPBM;

    // ---- layer 0: 4 -> 256, VALU; thread -> (sample, 4-col group), pair-wise ----
    if (tid < SPBM) xs4[tid] = *(const float4*)(x + (n0 + tid) * 4);
    __syncthreads();
#pragma unroll
    for (int rep = 0; rep < 2; ++rep) {
        const int idx = tid + 256 * rep;         // 0..511
        const int s   = idx >> 6;                // sample 0..7 (uniform per wave)
        const int cg  = idx & 63;                // 4-col group
        const float4 xv = xs4[s];
        unsigned int pk[2][8];
#pragma unroll
        for (int pr = 0; pr < 2; ++pr) {
            const int c = 4 * cg + 2 * pr;
            const float2 w0 = *(const float2*)(W0 + 0 * HDIM + c);
            const float2 w1 = *(const float2*)(W0 + 1 * HDIM + c);
            const float2 w2 = *(const float2*)(W0 + 2 * HDIM + c);
            const float2 w3 = *(const float2*)(W0 + 3 * HDIM + c);
            const float2 bb = *(const float2*)(b0 + c);
            const float u0 = xv.x*w0.x + xv.y*w1.x + xv.z*w2.x + xv.w*w3.x + bb.x;
            const float u1 = xv.x*w0.y + xv.y*w1.y + xv.z*w2.y + xv.w*w3.y + bb.y;
            const float ty0 = fast_tanh(u0), ty1 = fast_tanh(u1);
            const float t0 = 1.f - ty0 * ty0, t1 = 1.f - ty1 * ty1;
            const float m0 = -2.f * ty0 * t0, m1 = -2.f * ty1 * t1;
            pk[pr][0] = cvtpk(ty0, ty1);                      // ch0: tanh
            pk[pr][1] = cvtpk(t0 * w0.x, t1 * w0.y);          // ch1: t*w0
            pk[pr][2] = cvtpk(t0 * w1.x, t1 * w1.y);          // ch2: t*w1
            pk[pr][3] = cvtpk(t0 * w2.x, t1 * w2.y);          // ch3: t*w2
            pk[pr][4] = cvtpk(t0 * w3.x, t1 * w3.y);          // ch4: t*w3
            pk[pr][5] = cvtpk(m0 * w0.x * w0.x, m1 * w0.y * w0.y); // ch5
            pk[pr][6] = cvtpk(m0 * w1.x * w1.x, m1 * w1.y * w1.y); // ch6
            pk[pr][7] = cvtpk(m0 * w2.x * w2.x, m1 * w2.y * w2.y); // ch7
        }
        // permuted rows: ch0..3 at R.., ch4..7 at R+16..;  R = 32*(s>>2)+4*(s&3)
        u16* yr = Y + (32 * (s >> 2) + 4 * (s & 3)) * YP + 4 * cg;
#pragma unroll
        for (int j = 0; j < 4; ++j) {
            *(uint2*)(yr + j * YP)        = (uint2){pk[0][j],     pk[1][j]};
            *(uint2*)(yr + (16 + j) * YP) = (uint2){pk[0][4 + j], pk[1][4 + j]};
        }
    }
    __syncthreads();

    // ---- 3 hidden layers on the matrix pipe ----
    hidden_layer_mfma(Y, Wt + 0 * 65536, b1, l, wv);
    hidden_layer_mfma(Y, Wt + 1 * 65536, b2, l, wv);
    hidden_layer_mfma(Y, Wt + 2 * 65536, b3, l, wv);

    // ---- output head on MFMA: wave wv takes physical rows wv*16..wv*16+15 ----
    {
        const u16* wob = Wt + 3 * 65536;
        f32x4 h = (f32x4){0.f, 0.f, 0.f, 0.f};
#pragma unroll
        for (int ks = 0; ks < 8; ++ks) {
            const int kk = ks * 32 + lk8;
            const short8 a = *(const short8*)(Y + (wv * 16 + lm) * YP + kk);
            short8 bfr = (short8){0,0,0,0,0,0,0,0};
            if (lm < 2) bfr = *(const short8*)(wob + lm * 256 + kk);
            h = __builtin_amdgcn_mfma_f32_16x16x32_bf16(a, bfr, h, 0, 0, 0);
        }
        if (lm < 2) {
#pragma unroll
            for (int r = 0; r < 4; ++r)
                part[wv * 16 + (l >> 4) * 4 + r][lm] = h[r];
        }
    }
    __syncthreads();

    if (tid < SPBM) {
        const int s = tid;
        float q0[8], q1[8];
#pragma unroll
        for (int ch = 0; ch < 8; ++ch) {
            const int R = 32 * (s >> 2) + 16 * (ch >> 2) + 4 * (s & 3) + (ch & 3);
            q0[ch] = part[R][0];
            q1[ch] = part[R][1];
        }
        const float c0  = q0[0] + bo[0];
        const float Fi  = q1[0] + bo[1];
        const float cg0 = q0[1], cg1 = q0[2], cg2 = q0[3];
        const float ct  = q0[4];                 // dc/dx_3 (TDIM)
        const float fg0 = q1[1], fg1 = q1[2], fg2 = q1[3];
        const float trHc  = q0[5] + q0[6] + q0[7];
        const float fiLap = q1[5] + q1[6] + q1[7];
        const float jd = -trHc
                         - (cg0 * fg0 + cg1 * fg1 + cg2 * fg2 + c0 * fiLap)
                         + 0.1f * (cg0 + cg1 + cg2);
        const int n = n0 + s;
        out[0 * nB + n]         = c0;
        out[1 * nB + n]         = ct;
        out[2 * nB + 3 * n + 0] = cg0;
        out[2 * nB + 3 * n + 1] = cg1;
        out[2 * nB + 3 * n + 2] = cg2;
        out[5 * nB + n]         = Fi;
        out[6 * nB + 3 * n + 0] = fg0;
        out[6 * nB + 3 * n + 1] = fg1;
        out[6 * nB + 3 * n + 2] = fg2;
        out[9 * nB + n]         = fiLap;
        out[10 * nB + n]        = jd;
    }
}

extern "C" void kernel_launch(void* const* d_in, const int* in_sizes, int n_in,
                              void* d_out, int out_size, void* d_ws, size_t ws_size,
                              hipStream_t stream) {
    const float* x  = (const float*)d_in[0];
    const float* W0 = (const float*)d_in[1];
    const float* b0 = (const float*)d_in[2];
    const float* W1 = (const float*)d_in[3];
    const float* b1 = (const float*)d_in[4];
    const float* W2 = (const float*)d_in[5];
    const float* b2 = (const float*)d_in[6];
    const float* W3 = (const float*)d_in[7];
    const float* b3 = (const float*)d_in[8];
    const float* Wo = (const float*)d_in[9];
    const float* bo = (const float*)d_in[10];
    float* out = (float*)d_out;
    u16*   Wt  = (u16*)d_ws;                 // 3*65536 + 512 bf16 ≈ 385 KB

    const int nB = in_sizes[0] / 4;          // 16384

    hipLaunchKernelGGL(prep_w, dim3(97), dim3(256), 0, stream, W1, W2, W3, Wo, Wt);
    hipLaunchKernelGGL(mlp_jet_mfma, dim3(nB / SPBM), dim3(256), 0, stream,
                       x, W0, b0, b1, b2, b3, bo, Wt, out, nB);
}